// Round 10
// baseline (129.742 us; speedup 1.0000x reference)
//
#include <hip/hip_runtime.h>
#include <cmath>

// SSIM stability loss: 1 - mean(SSIM(x,y)), 11x11 Gaussian (sigma=1.5), zero SAME
// padding, fp32, 32 x 1 x 512 x 512.
//
// R24: FORCED residency via one 1024-thread block per CU. Evidence: busy%
// pinned ~44% across grids/barriers/ILP/MLP (R15-R23); OccupancyPercent
// ~15% at 512 AND 1024 blocks, ~9% at 256 -> co-residency never exceeds
// ~1.2 blocks/CU, so each 4-wave block runs ~1 wave/SIMD, and a lone wave
// of this code issues at ~44%. A block is atomic: all waves co-resident.
// So build 1024-thread blocks = 16 waves = 4 waves/SIMD, grid 256 = 1/CU.
// Block = 2 sub-bands, each 512 threads x (512 cols full width, 32-row
// band), per-sub-band 11-row LDS chunk (46.4 KB) -> 92.9 KB dynamic LDS.
// Inner loop = R19 proven: sum/diff channels u=(x+y)/sqrt2, v=(x-y)/sqrt2
// + squares, 6 aligned ds_read_b128/row, parity-folded 12-tap weight vec,
// 11-deep circular history, 2 barriers/chunk, fp64 atomic finish.
// Cost: halo 42/32 = 1.3125 (+13.5% H work vs R19, same as R21).
//
// Predict: Occupancy 15 -> ~45-50 (primary diagnostic). If TLP-starvation
// theory right: VALUBusy 43 -> 65-85%, dur 42.6 -> 22-28us. If dur ~42+ at
// forced 16 waves/CU -> theory refuted, structural plateau, declare next.
// VGPR <= 128 (launch_bounds cap; code ~100). Tripwire: WRITE_SIZE ~32B.

#define IMG   512
#define BROWS 32             // rows per sub-band
#define SUBS  2              // sub-bands per block (block covers 64 rows)
#define NHROW (BROWS + 10)   // 42 H-rows per sub-band
#define NCHUNK 4             // ceil(42/11)
#define CHR   11             // rows per LDS chunk (== history depth)
#define LCOLS 528            // staged cols -8..519 (full width + halo)
#define LUNITS 132           // float4 quads per staged row
#define UNITS_ROW 264        // v4f units per staged row
#define NQ (CHR * LUNITS)    // 1452 quads per chunk per sub-band
#define SUB_LDS (CHR * UNITS_ROW)          // v4f units per sub-band tile
#define LDS_BYTES (SUBS * SUB_LDS * 16)    // 92928
#define NBLOCKS 256
#define NPIX  8388608.0
#define RSQRT2 0.70710678118654752f

typedef float v2f __attribute__((ext_vector_type(2)));
typedef float v4f __attribute__((ext_vector_type(4)));

struct GaussW { float w[11]; };

__global__ __launch_bounds__(1024)
void ssim_stream_kernel(const float* __restrict__ x, const float* __restrict__ y,
                        double* __restrict__ acc_ws, unsigned long long* __restrict__ ctr,
                        float* __restrict__ out, GaussW gw) {
    extern __shared__ v4f dsm[];        // [SUBS][CHR][UNITS_ROW]
    __shared__ float wavesum[16];

    const int tid = threadIdx.x;
    const int sub = tid >> 9;           // sub-band 0/1
    const int t   = tid & 511;          // col within sub-band (1 col/thread)
    v4f (*tile4)[UNITS_ROW] = reinterpret_cast<v4f (*)[UNITS_ROW]>(dsm + sub * SUB_LDS);

    const int r0 = blockIdx.x * (SUBS * BROWS) + sub * BROWS;
    const size_t img_off = (size_t)blockIdx.y * (IMG * IMG);
    const float* __restrict__ xb = x + img_off;
    const float* __restrict__ yb = y + img_off;

    // output col = t; taps at staged cols t+3 .. t+13 (stage base -8).
    const int ub = (t + 3) >> 1;        // v4f unit of aligned window base
    const int p  = (t + 3) & 1;         // parity: tap k sits at window pos p+k

    // 12-tap per-lane weight vector: window pos m covers staged col 2*ub + m;
    // logical tap k = m - p, so wv2[m] = w[m-p] (0 outside [0,10]).
    v2f wv2[12];
    #pragma unroll
    for (int m = 0; m < 12; ++m) {
        float lo = (m <= 10) ? gw.w[m] : 0.f;       // p == 0
        float hi = (m >= 1) ? gw.w[m - 1] : 0.f;    // p == 1
        float wm = p ? hi : lo;
        wv2[m][0] = wm; wv2[m][1] = wm;
    }
    v2f wp[11];                          // vertical weights (parity-free)
    #pragma unroll
    for (int k = 0; k < 11; ++k) { wp[k][0] = gw.w[k]; wp[k][1] = gw.w[k]; }

    float4 sxr[3], syr[3];   // staged regs for next chunk (3 x 512 thr >= 1452)

    auto load_chunk = [&](int c) {
        #pragma unroll
        for (int it = 0; it < 3; ++it) {
            int idx = t + it * 512;
            int row = idx / LUNITS;
            int q   = idx - row * LUNITS;
            int gr = r0 - 5 + c * CHR + row;       // global image row
            int gc = -8 + q * 4;                   // global col of float4 (16B aligned)
            float4 vx = make_float4(0.f, 0.f, 0.f, 0.f);
            float4 vy = vx;
            if (idx < NQ && (unsigned)gr < IMG && (unsigned)gc < IMG) {
                const float* px = xb + (size_t)gr * IMG + gc;
                const float* py = yb + (size_t)gr * IMG + gc;
                vx = *(const float4*)px;
                vy = *(const float4*)py;
            }
            sxr[it] = vx; syr[it] = vy;
        }
    };
    // stage as u=(x+y)/sqrt2, v=(x-y)/sqrt2 (zero padding maps to zero: linear)
    auto store_chunk = [&]() {
        #pragma unroll
        for (int it = 0; it < 3; ++it) {
            int idx = t + it * 512;
            if (idx < NQ) {
                int row = idx / LUNITS;
                int q   = idx - row * LUNITS;
                const float4 vx = sxr[it], vy = syr[it];
                tile4[row][q * 2]     = (v4f){(vx.x + vy.x) * RSQRT2, (vx.x - vy.x) * RSQRT2,
                                              (vx.y + vy.y) * RSQRT2, (vx.y - vy.y) * RSQRT2};
                tile4[row][q * 2 + 1] = (v4f){(vx.z + vy.z) * RSQRT2, (vx.z - vy.z) * RSQRT2,
                                              (vx.w + vy.w) * RSQRT2, (vx.w - vy.w) * RSQRT2};
            }
        }
    };

    v2f histL[11];     // (hu, hv)     -- linear channel H-conv results
    v2f histQ[11];     // (huu, hvv)   -- quadratic channel H-conv results
    float lsum = 0.f;
    const float C1 = 1e-4f, C2 = 9e-4f;

    load_chunk(0);
    store_chunk();
    __syncthreads();

    #pragma unroll 1
    for (int c = 0; c < NCHUNK; ++c) {      // 4 chunks x 11 rows = 44 >= 42
        if (c < NCHUNK - 1) load_chunk(c + 1);  // global loads overlap chunk-c compute

        #pragma unroll
        for (int s = 0; s < CHR; ++s) {     // H-row m = 11c + s; hist slot = s
            if (!(c == NCHUNK - 1 && s >= NHROW - (NCHUNK - 1) * CHR)) {   // m < 42
                v4f w6[6];
                #pragma unroll
                for (int i = 0; i < 6; ++i) w6[i] = tile4[s][ub + i];

                // --- horizontal conv: 12 taps, 3 packed ops each ---
                v2f hL = (v2f){0.f, 0.f};
                v2f hQ = (v2f){0.f, 0.f};
                #pragma unroll
                for (int m = 0; m < 12; ++m) {
                    v2f tt = (m & 1) ? w6[m >> 1].zw : w6[m >> 1].xy;
                    hL = __builtin_elementwise_fma(wv2[m], tt, hL);  // v_pk_fma_f32
                    v2f q = tt * tt;                                 // v_pk_mul_f32
                    hQ = __builtin_elementwise_fma(wv2[m], q, hQ);   // v_pk_fma_f32
                }
                histL[s] = hL; histQ[s] = hQ;

                // --- output row (11c + s - 10) completes now ---
                if (c > 0 || s == 10) {
                    v2f aL = (v2f){0.f, 0.f};
                    v2f aQ = (v2f){0.f, 0.f};
                    #pragma unroll
                    for (int j = 0; j < 11; ++j) {
                        const int sl = (s + 1 + j) % 11;   // static per (s,j)
                        aL = __builtin_elementwise_fma(wp[j], histL[sl], aL);
                        aQ = __builtin_elementwise_fma(wp[j], histQ[sl], aQ);
                    }
                    // Mu=aL[0], Mv=aL[1], Qu=aQ[0], Qv=aQ[1]
                    float a = aL[0] * aL[0], b = aL[1] * aL[1];
                    float dm = a - b;              // = 2 mx my
                    float sm = a + b;              // = mx^2 + my^2
                    float num = (dm + C1) * ((aQ[0] - aQ[1]) - dm + C2);  // 2sxy
                    float den = (sm + C1) * ((aQ[0] + aQ[1]) - sm + C2);  // sx2+sy2
                    lsum += num * __builtin_amdgcn_rcpf(den);
                }
            }
        }

        __syncthreads();                    // everyone done reading tile
        if (c < NCHUNK - 1) { store_chunk(); __syncthreads(); }
    }

    // ---- reduction: wave shuffle -> LDS -> block partial -> fp64 atomic ----
    #pragma unroll
    for (int off = 32; off > 0; off >>= 1)
        lsum += __shfl_down(lsum, off, 64);
    if ((tid & 63) == 0) wavesum[tid >> 6] = lsum;
    __syncthreads();
    if (tid == 0) {
        float bs = 0.f;
        #pragma unroll
        for (int i = 0; i < 16; ++i) bs += wavesum[i];
        atomicAdd(acc_ws, (double)bs);
        __threadfence();
        unsigned long long old = atomicAdd(ctr, 1ull);
        if (old == (unsigned long long)(NBLOCKS - 1)) {
            __threadfence();
            double total = atomicAdd(acc_ws, 0.0);   // atomic RMW sees all prior adds
            out[0] = (float)(1.0 - total / NPIX);
        }
    }
}

extern "C" void kernel_launch(void* const* d_in, const int* in_sizes, int n_in,
                              void* d_out, int out_size, void* d_ws, size_t ws_size,
                              hipStream_t stream) {
    const float* x = (const float*)d_in[0];   // heatmap_clean
    const float* y = (const float*)d_in[1];   // heatmap_adv
    float* out = (float*)d_out;
    double* acc = (double*)d_ws;
    unsigned long long* ctr = (unsigned long long*)((char*)d_ws + 8);

    // allow > 64 KB dynamic LDS (host-side attribute set; not a stream op,
    // graph-capture safe; idempotent)
    static bool attr_set = false;
    if (!attr_set) {
        hipFuncSetAttribute(reinterpret_cast<const void*>(ssim_stream_kernel),
                            hipFuncAttributeMaxDynamicSharedMemorySize, LDS_BYTES);
        attr_set = true;
    }

    // zero the 16B of accumulator+counter state (capture-safe async memset)
    hipMemsetAsync(d_ws, 0, 16, stream);

    GaussW gw;
    double g[11], s = 0.0;
    for (int i = 0; i < 11; ++i) { double d = i - 5; g[i] = exp(-(d * d) / 4.5); s += g[i]; }
    for (int i = 0; i < 11; ++i) gw.w[i] = (float)(g[i] / s);

    dim3 grid(IMG / (SUBS * BROWS), 32);   // (8, 32) = 256 blocks = 1 per CU
    ssim_stream_kernel<<<grid, 1024, LDS_BYTES, stream>>>(x, y, acc, ctr, out, gw);
}

// Round 11
// 118.340 us; speedup vs baseline: 1.0964x; 1.0964x over previous
//
#include <hip/hip_runtime.h>
#include <cmath>

// SSIM stability loss: 1 - mean(SSIM(x,y)), 11x11 Gaussian (sigma=1.5), zero SAME
// padding, fp32, 32 x 1 x 512 x 512.
//
// R25: forced 8-wave residency, spill-free. R24 proved big blocks force
// occupancy (15 -> 36.5%) but hipcc caps 1024-thr blocks at 64 VGPR ->
// 29 MB scratch spill ate the gain (VALUBusy 35%). 512-thr blocks cap at
// 128 VGPR (launchability = 2 waves/SIMD); natural need ~72-100 -> no spill.
// One block = 8 waves atomic -> 8 waves/CU co-resident guaranteed (R19
// achieved only ~4.8 effective per OccupancyPercent).
//
// Geometry: 512 threads = full 512-col row (1 col/thread) x 64-row band;
// single 46.5 KB LDS tile (11-row chunk of v4f (u0,v0,u1,v1) units, 528
// staged cols incl. +-8 halo); grid (8,32) = 256 blocks = 1/CU. No column
// strip halo (full width) -> less staging than R19. Work/px == R19.
//
// Inner loop = R19 proven: sum/diff channels (now UNSCALED u=x+y, v=x-y;
// factors folded into constants: ratio = (dm+2C1)(dq-dm+2C2) /
// ((sm+2C1)(sq-sm+2C2)) -- algebraically identical, saves staging muls);
// 6 aligned ds_read_b128/row; parity-folded 12-tap weight vector; 11-deep
// circular register history; 2 barriers/chunk; fp64 atomic finish.
//
// Predict: Occupancy 15 -> ~24-25 (primary diagnostic). If TLP theory right:
// VALUBusy 43 -> 55-62%, dur 42.6 -> 32-37us. Neutral ~42 => TLP refuted,
// structural plateau, declare. Tripwires: VGPR 72-100, WRITE_SIZE ~32B
// (spill invalidates the experiment). FETCH ~41MB, LDS 46.6KB.

#define IMG   512
#define BROWS 64
#define NHROW (BROWS + 10)   // 74 H-rows per band
#define NCHUNK 7             // ceil(74/11)
#define CHR   11             // rows per LDS chunk (== history depth)
#define LCOLS 528            // staged cols -8..519 (full width + halo)
#define LUNITS 132           // float4 quads per staged row
#define UNITS_ROW 264        // v4f units per staged row
#define NQ (CHR * LUNITS)    // 1452 quads per chunk
#define NBLOCKS 256
#define NPIX  8388608.0

typedef float v2f __attribute__((ext_vector_type(2)));
typedef float v4f __attribute__((ext_vector_type(4)));

struct GaussW { float w[11]; };

__global__ __launch_bounds__(512, 1)
void ssim_stream_kernel(const float* __restrict__ x, const float* __restrict__ y,
                        double* __restrict__ acc_ws, unsigned long long* __restrict__ ctr,
                        float* __restrict__ out, GaussW gw) {
    // tile4[s][u] = staged cols (2u-8, 2u-7) packed as (u0, v0, u1, v1)
    __shared__ v4f tile4[CHR][UNITS_ROW];   // 11 * 264 * 16 = 46464 B
    __shared__ float wavesum[8];

    const int tid = threadIdx.x;
    const int r0 = blockIdx.x * BROWS;
    const size_t img_off = (size_t)blockIdx.y * (IMG * IMG);
    const float* __restrict__ xb = x + img_off;
    const float* __restrict__ yb = y + img_off;

    // output col = tid; taps at staged cols tid+3 .. tid+13 (stage base -8),
    // i.e. global cols tid-5 .. tid+5. Aligned 6 x b128 window from unit ub.
    const int ci = tid;
    const int ub = (ci + 3) >> 1;       // v4f unit of aligned window base
    const int p  = (ci + 3) & 1;        // parity: tap k sits at window pos p+k

    // 12-tap per-lane weight vector: window pos m covers staged col 2*ub + m;
    // logical tap k = m - p, so wv2[m] = w[m-p] (0 outside [0,10]).
    v2f wv2[12];
    #pragma unroll
    for (int m = 0; m < 12; ++m) {
        float lo = (m <= 10) ? gw.w[m] : 0.f;       // p == 0
        float hi = (m >= 1) ? gw.w[m - 1] : 0.f;    // p == 1
        float wm = p ? hi : lo;
        wv2[m][0] = wm; wv2[m][1] = wm;
    }
    v2f wp[11];                          // vertical weights (parity-free)
    #pragma unroll
    for (int k = 0; k < 11; ++k) { wp[k][0] = gw.w[k]; wp[k][1] = gw.w[k]; }

    float4 sxr[3], syr[3];   // staged regs for next chunk (3 x 512 thr >= 1452)

    auto load_chunk = [&](int c) {
        #pragma unroll
        for (int it = 0; it < 3; ++it) {
            int idx = tid + it * 512;
            int row = idx / LUNITS;
            int q   = idx - row * LUNITS;
            int gr = r0 - 5 + c * CHR + row;       // global image row
            int gc = -8 + q * 4;                   // global col of float4 (16B aligned)
            float4 vx = make_float4(0.f, 0.f, 0.f, 0.f);
            float4 vy = vx;
            if (idx < NQ && (unsigned)gr < IMG && (unsigned)gc < IMG) {
                const float* px = xb + (size_t)gr * IMG + gc;
                const float* py = yb + (size_t)gr * IMG + gc;
                vx = *(const float4*)px;
                vy = *(const float4*)py;
            }
            sxr[it] = vx; syr[it] = vy;
        }
    };
    // stage as u=x+y, v=x-y (unscaled; zero padding maps to zero: linear)
    auto store_chunk = [&]() {
        #pragma unroll
        for (int it = 0; it < 3; ++it) {
            int idx = tid + it * 512;
            if (idx < NQ) {
                int row = idx / LUNITS;
                int q   = idx - row * LUNITS;
                const float4 vx = sxr[it], vy = syr[it];
                tile4[row][q * 2]     = (v4f){vx.x + vy.x, vx.x - vy.x,
                                              vx.y + vy.y, vx.y - vy.y};
                tile4[row][q * 2 + 1] = (v4f){vx.z + vy.z, vx.z - vy.z,
                                              vx.w + vy.w, vx.w - vy.w};
            }
        }
    };

    v2f histL[11];     // (hu, hv)     -- linear channel H-conv results
    v2f histQ[11];     // (huu, hvv)   -- quadratic channel H-conv results
    float lsum = 0.f;
    const float C1x2 = 2e-4f, C2x2 = 1.8e-3f;   // 2*C1, 2*C2 (unscaled u,v algebra)

    load_chunk(0);
    store_chunk();
    __syncthreads();

    #pragma unroll 1
    for (int c = 0; c < NCHUNK; ++c) {      // 7 chunks x 11 rows = 77 >= 74
        if (c < NCHUNK - 1) load_chunk(c + 1);  // global loads overlap chunk-c compute

        #pragma unroll
        for (int s = 0; s < CHR; ++s) {     // H-row m = 11c + s; hist slot = s
            if (!(c == NCHUNK - 1 && s >= NHROW - (NCHUNK - 1) * CHR)) {   // m < 74
                v4f w6[6];
                #pragma unroll
                for (int i = 0; i < 6; ++i) w6[i] = tile4[s][ub + i];

                // --- horizontal conv: 12 taps, 3 packed ops each ---
                v2f hL = (v2f){0.f, 0.f};
                v2f hQ = (v2f){0.f, 0.f};
                #pragma unroll
                for (int m = 0; m < 12; ++m) {
                    v2f t = (m & 1) ? w6[m >> 1].zw : w6[m >> 1].xy;
                    hL = __builtin_elementwise_fma(wv2[m], t, hL);   // v_pk_fma_f32
                    v2f q = t * t;                                   // v_pk_mul_f32
                    hQ = __builtin_elementwise_fma(wv2[m], q, hQ);   // v_pk_fma_f32
                }
                histL[s] = hL; histQ[s] = hQ;

                // --- output row (11c + s - 10) completes now ---
                if (c > 0 || s == 10) {
                    v2f aL = (v2f){0.f, 0.f};
                    v2f aQ = (v2f){0.f, 0.f};
                    #pragma unroll
                    for (int j = 0; j < 11; ++j) {
                        const int sl = (s + 1 + j) % 11;   // static per (s,j)
                        aL = __builtin_elementwise_fma(wp[j], histL[sl], aL);
                        aQ = __builtin_elementwise_fma(wp[j], histQ[sl], aQ);
                    }
                    // Mu=aL[0], Mv=aL[1], Qu=aQ[0], Qv=aQ[1]
                    float a = aL[0] * aL[0], b = aL[1] * aL[1];
                    float dm = a - b;              // = 4 mx my
                    float sm = a + b;              // = 2(mx^2 + my^2)
                    float num = (dm + C1x2) * ((aQ[0] - aQ[1]) - dm + C2x2);
                    float den = (sm + C1x2) * ((aQ[0] + aQ[1]) - sm + C2x2);
                    lsum += num * __builtin_amdgcn_rcpf(den);
                }
            }
        }

        __syncthreads();                    // everyone done reading tile
        if (c < NCHUNK - 1) { store_chunk(); __syncthreads(); }
    }

    // ---- reduction: wave shuffle -> LDS -> block partial -> fp64 atomic ----
    #pragma unroll
    for (int off = 32; off > 0; off >>= 1)
        lsum += __shfl_down(lsum, off, 64);
    if ((tid & 63) == 0) wavesum[tid >> 6] = lsum;
    __syncthreads();
    if (tid == 0) {
        float bs = 0.f;
        #pragma unroll
        for (int i = 0; i < 8; ++i) bs += wavesum[i];
        atomicAdd(acc_ws, (double)bs);
        __threadfence();
        unsigned long long old = atomicAdd(ctr, 1ull);
        if (old == (unsigned long long)(NBLOCKS - 1)) {
            __threadfence();
            double total = atomicAdd(acc_ws, 0.0);   // atomic RMW sees all prior adds
            out[0] = (float)(1.0 - total / NPIX);
        }
    }
}

extern "C" void kernel_launch(void* const* d_in, const int* in_sizes, int n_in,
                              void* d_out, int out_size, void* d_ws, size_t ws_size,
                              hipStream_t stream) {
    const float* x = (const float*)d_in[0];   // heatmap_clean
    const float* y = (const float*)d_in[1];   // heatmap_adv
    float* out = (float*)d_out;
    double* acc = (double*)d_ws;
    unsigned long long* ctr = (unsigned long long*)((char*)d_ws + 8);

    // zero the 16B of accumulator+counter state (capture-safe async memset)
    hipMemsetAsync(d_ws, 0, 16, stream);

    GaussW gw;
    double g[11], s = 0.0;
    for (int i = 0; i < 11; ++i) { double d = i - 5; g[i] = exp(-(d * d) / 4.5); s += g[i]; }
    for (int i = 0; i < 11; ++i) gw.w[i] = (float)(g[i] / s);

    dim3 grid(IMG / BROWS, 32);   // (8, 32) = 256 blocks = 1 per CU, 8 waves forced
    ssim_stream_kernel<<<grid, 512, 0, stream>>>(x, y, acc, ctr, out, gw);
}

// Round 12
// 115.381 us; speedup vs baseline: 1.1245x; 1.0256x over previous
//
#include <hip/hip_runtime.h>
#include <cmath>

// SSIM stability loss: 1 - mean(SSIM(x,y)), 11x11 Gaussian (sigma=1.5), zero SAME
// padding, fp32, 32 x 1 x 512 x 512.
//
// R26: barrier-free per-wave tiles (R23) x forced residency (R24/25).
// Evidence: R24/R25 prove big blocks FORCE waves co-resident (occ 15->36.5)
// but block-wide barriers serialize all waves -> slower. R23 proves
// barrier-free wave-private tiles decouple waves, but at 256-thr grids the
// dispatcher delivers only ~1.2 blocks/CU (occ ~15%). Combination: one
// 512-thread block per CU; its 8 waves are fully independent R23-style
// streams (private 64-col strip, private double-buffered LDS tile, zero
// main-loop barriers; in-wave DS ordering is the only sync - correctness
// proven by R23). 8 independent waves/CU forced co-resident.
// Per-CU pipe balance at 8 waves: LDS 8x6x12=576 cyc/row-step vs VALU
// 2x68x4=544 cyc/SIMD -- balanced, the ideal operating point.
//
// LDS: 8 waves x 2 buf x 11 rows x 40 v4f units x 16 B = 112,640 B dynamic
// (hipFuncSetAttribute, proven R24). Strip: 64 out cols + 80 staged cols
// (1.25x fetch redundancy, memory not binding). Inner loop = R19/R25:
// unscaled sum/diff channels u=x+y, v=x-y + squares (2C1/2C2 algebra,
// verified R25); 6 aligned ds_read_b128/row; parity-folded 12-tap weights;
// 11-deep circular history; fp64 atomic finish. launch_bounds(512,1) ->
// VGPR cap 128, natural ~90, no spill (R25 compiled 72 at this bound).
//
// Predict: occ 15 -> ~25; if independence x residency is the lever:
// VALUBusy 43 -> 55-65%, dur 42.6 -> 28-34us. Tripwires: VGPR <= 128,
// WRITE_SIZE ~32B, absmax 0. Neutral ~43+ clean => structural plateau,
// declare next round.

#define IMG   512
#define BROWS 64
#define NHROW (BROWS + 10)   // 74 H-rows per band
#define NCHUNK 7             // ceil(74/11)
#define CHR   11             // rows per LDS chunk (== history depth)
#define WQUADS 20            // float4 col-quads staged per row per wave (80 cols)
#define WUNITS 40            // v4f units per staged row per wave
#define NQ (CHR * WQUADS)    // 220 quads per chunk per wave
#define WAVE_LDS (2 * CHR * WUNITS)        // v4f units per wave (dbuf)
#define LDS_BYTES (8 * WAVE_LDS * 16)      // 112640
#define NBLOCKS 256
#define NPIX  8388608.0

typedef float v2f __attribute__((ext_vector_type(2)));
typedef float v4f __attribute__((ext_vector_type(4)));

struct GaussW { float w[11]; };

__global__ __launch_bounds__(512, 1)
void ssim_stream_kernel(const float* __restrict__ x, const float* __restrict__ y,
                        double* __restrict__ acc_ws, unsigned long long* __restrict__ ctr,
                        float* __restrict__ out, GaussW gw) {
    extern __shared__ v4f dsm[];        // [8 waves][2 bufs][CHR][WUNITS]
    __shared__ float wavesum[8];

    const int tid  = threadIdx.x;
    const int w    = tid >> 6;          // wave id 0..7, owns a 64-col strip
    const int lane = tid & 63;
    const int c0 = w * 64;              // strip base col (block covers all 512)
    const int r0 = blockIdx.x * BROWS;
    const size_t img_off = (size_t)blockIdx.y * (IMG * IMG);
    const float* __restrict__ xb = x + img_off;
    const float* __restrict__ yb = y + img_off;

    v4f (*wtile)[CHR][WUNITS] =
        reinterpret_cast<v4f (*)[CHR][WUNITS]>(dsm + (size_t)w * WAVE_LDS);

    // lane's output col = c0 + lane; taps at staged cols lane+3 .. lane+13
    // (stage base c0-8). Aligned 6 x b128 window starting at unit ub.
    const int ub = (lane + 3) >> 1;
    const int p  = (lane + 3) & 1;      // parity: tap k sits at window pos p+k

    // 12-tap per-lane weight vector: window pos m covers staged col 2*ub + m;
    // logical tap k = m - p, so wv2[m] = w[m-p] (0 outside [0,10]).
    v2f wv2[12];
    #pragma unroll
    for (int m = 0; m < 12; ++m) {
        float lo = (m <= 10) ? gw.w[m] : 0.f;       // p == 0
        float hi = (m >= 1) ? gw.w[m - 1] : 0.f;    // p == 1
        float wm = p ? hi : lo;
        wv2[m][0] = wm; wv2[m][1] = wm;
    }
    v2f wp[11];                          // vertical weights (parity-free)
    #pragma unroll
    for (int k = 0; k < 11; ++k) { wp[k][0] = gw.w[k]; wp[k][1] = gw.w[k]; }

    float4 sxr[4], syr[4];   // staged regs for next chunk (4 iters x 64 lanes >= 220)

    auto load_chunk = [&](int c) {
        #pragma unroll
        for (int it = 0; it < 4; ++it) {
            int idx = lane + it * 64;
            int row = idx / WQUADS;
            int q   = idx - row * WQUADS;
            int gr = r0 - 5 + c * CHR + row;       // global image row
            int gc = c0 - 8 + q * 4;               // global col of float4 (16B aligned)
            float4 vx = make_float4(0.f, 0.f, 0.f, 0.f);
            float4 vy = vx;
            if (idx < NQ && (unsigned)gr < IMG && (unsigned)gc < IMG) {
                const float* px = xb + (size_t)gr * IMG + gc;
                const float* py = yb + (size_t)gr * IMG + gc;
                vx = *(const float4*)px;
                vy = *(const float4*)py;
            }
            sxr[it] = vx; syr[it] = vy;
        }
    };
    // stage as u=x+y, v=x-y (unscaled; zero padding maps to zero: linear)
    auto store_chunk = [&](int b) {
        #pragma unroll
        for (int it = 0; it < 4; ++it) {
            int idx = lane + it * 64;
            if (idx < NQ) {
                int row = idx / WQUADS;
                int q   = idx - row * WQUADS;
                const float4 vx = sxr[it], vy = syr[it];
                wtile[b][row][q * 2]     = (v4f){vx.x + vy.x, vx.x - vy.x,
                                                 vx.y + vy.y, vx.y - vy.y};
                wtile[b][row][q * 2 + 1] = (v4f){vx.z + vy.z, vx.z - vy.z,
                                                 vx.w + vy.w, vx.w - vy.w};
            }
        }
    };

    v2f histL[11];     // (hu, hv)     -- linear channel H-conv results
    v2f histQ[11];     // (huu, hvv)   -- quadratic channel H-conv results
    float lsum = 0.f;
    const float C1x2 = 2e-4f, C2x2 = 1.8e-3f;   // 2*C1, 2*C2 (unscaled algebra)

    load_chunk(0);
    store_chunk(0);
    // no barrier: DS ops of one wave complete in order; compiler inserts the
    // lgkmcnt before the first dependent ds_read use.

    #pragma unroll 1
    for (int c = 0; c < NCHUNK; ++c) {      // 7 chunks x 11 rows = 77 >= 74
        const int b = c & 1;
        if (c < NCHUNK - 1) load_chunk(c + 1);  // global loads overlap chunk-c compute

        #pragma unroll
        for (int s = 0; s < CHR; ++s) {     // H-row m = 11c + s; hist slot = s
            if (!(c == NCHUNK - 1 && s >= NHROW - (NCHUNK - 1) * CHR)) {   // m < 74
                v4f w6[6];
                #pragma unroll
                for (int i = 0; i < 6; ++i) w6[i] = wtile[b][s][ub + i];

                // --- horizontal conv: 12 taps, 3 packed ops each ---
                v2f hL = (v2f){0.f, 0.f};
                v2f hQ = (v2f){0.f, 0.f};
                #pragma unroll
                for (int m = 0; m < 12; ++m) {
                    v2f t = (m & 1) ? w6[m >> 1].zw : w6[m >> 1].xy;
                    hL = __builtin_elementwise_fma(wv2[m], t, hL);   // v_pk_fma_f32
                    v2f q = t * t;                                   // v_pk_mul_f32
                    hQ = __builtin_elementwise_fma(wv2[m], q, hQ);   // v_pk_fma_f32
                }
                histL[s] = hL; histQ[s] = hQ;

                // --- output row (11c + s - 10) completes now ---
                if (c > 0 || s == 10) {
                    v2f aL = (v2f){0.f, 0.f};
                    v2f aQ = (v2f){0.f, 0.f};
                    #pragma unroll
                    for (int j = 0; j < 11; ++j) {
                        const int sl = (s + 1 + j) % 11;   // static per (s,j)
                        aL = __builtin_elementwise_fma(wp[j], histL[sl], aL);
                        aQ = __builtin_elementwise_fma(wp[j], histQ[sl], aQ);
                    }
                    float a = aL[0] * aL[0], bq = aL[1] * aL[1];
                    float dm = a - bq;             // = 4 mx my
                    float sm = a + bq;             // = 2(mx^2 + my^2)
                    float num = (dm + C1x2) * ((aQ[0] - aQ[1]) - dm + C2x2);
                    float den = (sm + C1x2) * ((aQ[0] + aQ[1]) - sm + C2x2);
                    lsum += num * __builtin_amdgcn_rcpf(den);
                }
            }
        }

        // write next chunk into this wave's OTHER buffer -- no barrier needed,
        // reads of buffer b above are older DS ops of the same wave (in-order).
        if (c < NCHUNK - 1) store_chunk(b ^ 1);
    }

    // ---- reduction: wave shuffle -> LDS -> block partial -> fp64 atomic ----
    #pragma unroll
    for (int off = 32; off > 0; off >>= 1)
        lsum += __shfl_down(lsum, off, 64);
    if (lane == 0) wavesum[w] = lsum;
    __syncthreads();
    if (tid == 0) {
        float bs = 0.f;
        #pragma unroll
        for (int i = 0; i < 8; ++i) bs += wavesum[i];
        atomicAdd(acc_ws, (double)bs);
        __threadfence();
        unsigned long long old = atomicAdd(ctr, 1ull);
        if (old == (unsigned long long)(NBLOCKS - 1)) {
            __threadfence();
            double total = atomicAdd(acc_ws, 0.0);   // atomic RMW sees all prior adds
            out[0] = (float)(1.0 - total / NPIX);
        }
    }
}

extern "C" void kernel_launch(void* const* d_in, const int* in_sizes, int n_in,
                              void* d_out, int out_size, void* d_ws, size_t ws_size,
                              hipStream_t stream) {
    const float* x = (const float*)d_in[0];   // heatmap_clean
    const float* y = (const float*)d_in[1];   // heatmap_adv
    float* out = (float*)d_out;
    double* acc = (double*)d_ws;
    unsigned long long* ctr = (unsigned long long*)((char*)d_ws + 8);

    // allow > 64 KB dynamic LDS (host-side attribute, graph-capture safe)
    static bool attr_set = false;
    if (!attr_set) {
        hipFuncSetAttribute(reinterpret_cast<const void*>(ssim_stream_kernel),
                            hipFuncAttributeMaxDynamicSharedMemorySize, LDS_BYTES);
        attr_set = true;
    }

    // zero the 16B of accumulator+counter state (capture-safe async memset)
    hipMemsetAsync(d_ws, 0, 16, stream);

    GaussW gw;
    double g[11], s = 0.0;
    for (int i = 0; i < 11; ++i) { double d = i - 5; g[i] = exp(-(d * d) / 4.5); s += g[i]; }
    for (int i = 0; i < 11; ++i) gw.w[i] = (float)(g[i] / s);

    dim3 grid(IMG / BROWS, 32);   // (8, 32) = 256 blocks = 1/CU, 8 indep waves forced
    ssim_stream_kernel<<<grid, 512, LDS_BYTES, stream>>>(x, y, acc, ctr, out, gw);
}